// Round 5
// baseline (690.167 us; speedup 1.0000x reference)
//
#include <hip/hip_runtime.h>

// ---------------------------------------------------------------------------
// RGCN (basis decomposition), 2 layers. N=50000, E=1e6, H=128, O=64, R=16.
// Round 5: round 4 was barrier-latency-bound (3 syncthreads/chunk, grid 500
// -> only ~8 waves/CU, MfmaUtil+VALUBusy < 30%). Changes:
//  - DSTBLK 64 -> grid 782, LDS 45 KB -> 3 blocks/CU (12 waves).
//  - 2 barriers/chunk: norm folded into pmat (pmat[dloc][e]=bf16(norm));
//    pmat maintained by clear-then-set from the owning handler lane (no
//    per-chunk zeroing, race-free by same-lane program order); ys columns are
//    wave-local so the ys barrier is gone.
//  - Register prefetch: next chunk's ebuf+gather global loads issue between
//    GEMM1 and the agg GEMM, staying in flight across S0 (loads-in-flight-
//    over-barrier pattern).
//  - ebuf packed to uint2 {src | dloc<<20, norm_f32}: scatter writes and
//    layer metadata reads halve; d/DSTBLK becomes d>>6.
// MFMA layouts identical to the passing round-4 kernel.
// ---------------------------------------------------------------------------

typedef short bf16x8 __attribute__((ext_vector_type(8)));
typedef float f32x4 __attribute__((ext_vector_type(4)));

#define RELS 16
#define HDIM 128
#define DSTBLK 64

__device__ inline unsigned short f2bf(float f) {
  unsigned int u = __float_as_uint(f);
  unsigned int r = u + 0x7FFFu + ((u >> 16) & 1u);
  return (unsigned short)(r >> 16);
}

__global__ void cvt_bf16(const float* __restrict__ in, unsigned short* __restrict__ out, int n8) {
  int i = blockIdx.x * blockDim.x + threadIdx.x;
  if (i >= n8) return;
  float4 a = ((const float4*)in)[i * 2];
  float4 b = ((const float4*)in)[i * 2 + 1];
  uint4 o;
  o.x = (unsigned)f2bf(a.x) | ((unsigned)f2bf(a.y) << 16);
  o.y = (unsigned)f2bf(a.z) | ((unsigned)f2bf(a.w) << 16);
  o.z = (unsigned)f2bf(b.x) | ((unsigned)f2bf(b.y) << 16);
  o.w = (unsigned)f2bf(b.z) | ((unsigned)f2bf(b.w) << 16);
  ((uint4*)out)[i] = o;
}

// Wt[r][o][k] (bf16, transposed) = sum_b comp[r,b] * V[b,k,o]
__global__ void compute_w(const float* __restrict__ comp, const float* __restrict__ V,
                          unsigned short* __restrict__ Wt, int IO) {
  int idx = blockIdx.x * blockDim.x + threadIdx.x;
  if (idx >= RELS * IO * HDIM) return;
  int k = idx & (HDIM - 1);
  int o = (idx >> 7) % IO;
  int r = idx / (IO * HDIM);
  float s = 0.f;
#pragma unroll
  for (int b = 0; b < RELS; b++)
    s = fmaf(comp[r * RELS + b], V[(size_t)b * HDIM * IO + (size_t)k * IO + o], s);
  Wt[idx] = f2bf(s);
}

__global__ void hist_bins(const int* __restrict__ dst, const int* __restrict__ etype,
                          int n, int nbins, int* __restrict__ counts) {
  __shared__ int lh[12544];
  for (int j = threadIdx.x; j < nbins; j += blockDim.x) lh[j] = 0;
  __syncthreads();
  for (int i = blockIdx.x * blockDim.x + threadIdx.x; i < n; i += gridDim.x * blockDim.x)
    atomicAdd(&lh[(dst[i] >> 6) * RELS + etype[i]], 1);
  __syncthreads();
  for (int j = threadIdx.x; j < nbins; j += blockDim.x) {
    int c = lh[j];
    if (c) atomicAdd(&counts[j], c);
  }
}

// exclusive scan of counts padded to multiples of 16
__global__ void scan_offsets(const int* __restrict__ counts, int* __restrict__ offsets, int nbins) {
  __shared__ int csum[257];
  const int t = threadIdx.x;
  const int CH = (nbins + 255) / 256;
  int lo = t * CH, hi = min(lo + CH, nbins);
  int s = 0;
  for (int i = lo; i < hi; i++) s += (counts[i] + 15) & ~15;
  csum[t + 1] = s;
  if (t == 0) csum[0] = 0;
  __syncthreads();
  if (t == 0)
    for (int i = 1; i <= 256; i++) csum[i] += csum[i - 1];
  __syncthreads();
  int run = csum[t];
  for (int i = lo; i < hi; i++) {
    offsets[i] = run;
    run += (counts[i] + 15) & ~15;
  }
  if (lo < hi && hi == nbins) offsets[nbins] = run;
}

// ebuf[p] = {src | dloc<<20, norm_f32_bits}; pad slots unwritten (validity
// from counts). Only real slots are ever used.
__global__ void scatter_bins(const int* __restrict__ src, const int* __restrict__ dst,
                             const int* __restrict__ etype, const float* __restrict__ norm,
                             int n, const int* __restrict__ offsets, int* __restrict__ cursor,
                             uint2* __restrict__ ebuf) {
  for (int i = blockIdx.x * blockDim.x + threadIdx.x; i < n; i += gridDim.x * blockDim.x) {
    int d = dst[i];
    int b = (d >> 6) * RELS + etype[i];
    int p = offsets[b] + atomicAdd(&cursor[b], 1);
    ebuf[p] = make_uint2((unsigned)src[i] | ((unsigned)(d & 63) << 20), __float_as_uint(norm[i]));
  }
}

// One block owns 64 destination nodes; walks its 16 relation bins in 64-edge
// chunks. Per chunk: [S0] write prefetched xs rows; handler lanes clear-then-
// set pmat[dloc][edge]=bf16(norm); [S2] GEMM1 (xs @ W_r) staged to wave-local
// ys^T columns; prefetch next chunk's global loads; agg GEMM pacc += P @ Y.
// Wave w owns output columns [w*OUT/4, +OUT/4).
template <int OUT, bool BF16_RELU_OUT>
__launch_bounds__(256, 3)
__global__ void rgcn_layer(const unsigned short* __restrict__ Xb,  // [N][128] bf16
                           const unsigned short* __restrict__ Wt,  // [R][OUT][128] bf16
                           const uint2* __restrict__ ebuf,
                           const int* __restrict__ offsets, const int* __restrict__ counts,
                           const float* __restrict__ bias, void* __restrict__ Hout,
                           int nNodes) {
  constexpr int NT = OUT / 64;  // 2 (OUT=128) or 1 (OUT=64)
  __shared__ __align__(16) unsigned short xs[64][136];   // 68 dw stride: 8 b128 bank-groups
  __shared__ __align__(16) unsigned short ys[OUT][72];   // messages^T [col][edge], wave-local cols
  __shared__ __align__(16) unsigned short pmat[64][72];  // P[dst_local][edge] = bf16(norm)

  const int t = threadIdx.x;
  const int w = t >> 6;
  const int lane = t & 63;
  const int quad = lane >> 4;
  const int l16 = lane & 15;
  const int r0 = t >> 4;     // gather row base (0..15)
  const int k8 = t & 15;     // gather 8-elem column piece
  const bool isHandler = (t & 3) == 0;
  const int myCol = t >> 2;  // handler-owned edge column (0..63)
  const int nodeBase = blockIdx.x * DSTBLK;
  const int binBase = blockIdx.x * RELS;
  const int colBase = w * (OUT / 4);

  // one-time zero: stale LDS may hold NaN bit patterns (0 * NaN = NaN)
  for (int i = t; i < 64 * 136 * 2 / 16; i += 256) ((uint4*)xs)[i] = make_uint4(0, 0, 0, 0);
  for (int i = t; i < OUT * 72 * 2 / 16; i += 256) ((uint4*)ys)[i] = make_uint4(0, 0, 0, 0);
  for (int i = t; i < 64 * 72 * 2 / 16; i += 256) ((uint4*)pmat)[i] = make_uint4(0, 0, 0, 0);

  f32x4 pacc[4][NT] = {};  // persistent dst accumulator

  // first nonempty bin
  int bin = 0, base = 0, binEnd = 0, realEnd = 0;
  for (; bin < RELS; bin++) {
    base = offsets[binBase + bin];
    binEnd = offsets[binBase + bin + 1];
    if (base < binEnd) { realEnd = base + counts[binBase + bin]; break; }
  }

  uint4 pr[4] = {};
  uint2 md = make_uint2(0, 0);
  bool mdValid = false, prevValid = false;
  int prevDloc = 0;
  bf16x8 wf[4][NT];
  int curRel = -1;

  if (bin < RELS) {  // prologue prefetch
    int nR = min(64, realEnd - base);
#pragma unroll
    for (int i = 0; i < 4; i++) {
      int row = i * 16 + r0;
      if (row < nR) {
        uint2 e = ebuf[base + row];
        pr[i] = *(const uint4*)(Xb + (size_t)(e.x & 0xFFFFFu) * HDIM + k8 * 8);
      }
    }
    if (isHandler && myCol < nR) { md = ebuf[base + myCol]; mdValid = true; }
  }

  while (bin < RELS) {
    const int nRows = min(64, realEnd - base);
    if (bin != curRel) {  // W fragments for this relation (register-resident)
      curRel = bin;
      const unsigned short* Wr = Wt + (size_t)bin * OUT * HDIM;
#pragma unroll
      for (int ks = 0; ks < 4; ks++)
#pragma unroll
        for (int nt = 0; nt < NT; nt++)
          wf[ks][nt] = *(const bf16x8*)(Wr + (size_t)(colBase + nt * 16 + l16) * HDIM + ks * 32 + quad * 8);
    }

    __syncthreads();  // S0: all waves' previous-chunk LDS reads done

    // ---- write phase (from prefetch registers) ----
#pragma unroll
    for (int i = 0; i < 4; i++) {
      int row = i * 16 + r0;
      if (row < nRows) *(uint4*)&xs[row][k8 * 8] = pr[i];
    }
    if (isHandler) {
      if (prevValid) pmat[prevDloc][myCol] = 0;  // clear old entry (same-lane order)
      if (mdValid) {
        int dl = (int)(md.x >> 20);
        pmat[dl][myCol] = f2bf(__uint_as_float(md.y));  // P = norm (bf16)
        prevDloc = dl;
        prevValid = true;
      } else {
        prevValid = false;
      }
    }

    __syncthreads();  // S2: xs + pmat visible

    // next chunk coords (scalar; s_load latency hides under GEMM1)
    int nbin = bin, nbase = base + 64, nbinEnd = binEnd, nrealEnd = realEnd;
    if (nbase >= binEnd) {
      for (nbin = bin + 1; nbin < RELS; nbin++) {
        nbase = offsets[binBase + nbin];
        nbinEnd = offsets[binBase + nbin + 1];
        if (nbase < nbinEnd) { nrealEnd = nbase + counts[binBase + nbin]; break; }
      }
    }

    // ---- GEMM1: messages Y = xs @ W_r, staged to wave-local ys^T columns ----
#pragma unroll
    for (int mt = 0; mt < 4; mt++) {
      if (mt * 16 < nRows) {  // wave-uniform
        f32x4 dacc[NT] = {};
#pragma unroll
        for (int ks = 0; ks < 4; ks++) {
          bf16x8 a = *(const bf16x8*)&xs[mt * 16 + l16][ks * 32 + quad * 8];
#pragma unroll
          for (int nt = 0; nt < NT; nt++)
            dacc[nt] = __builtin_amdgcn_mfma_f32_16x16x32_bf16(a, wf[ks][nt], dacc[nt], 0, 0, 0);
        }
#pragma unroll
        for (int nt = 0; nt < NT; nt++) {
          uint2 pk;
          pk.x = (unsigned)f2bf(dacc[nt][0]) | ((unsigned)f2bf(dacc[nt][1]) << 16);
          pk.y = (unsigned)f2bf(dacc[nt][2]) | ((unsigned)f2bf(dacc[nt][3]) << 16);
          *(uint2*)&ys[colBase + nt * 16 + l16][mt * 16 + quad * 4] = pk;
        }
      }
    }

    // ---- prefetch next chunk: loads stay in flight across agg + S0 ----
    mdValid = false;
    if (nbin < RELS) {
      int nR = min(64, nrealEnd - nbase);
#pragma unroll
      for (int i = 0; i < 4; i++) {
        int row = i * 16 + r0;
        if (row < nR) {
          uint2 e = ebuf[nbase + row];
          pr[i] = *(const uint4*)(Xb + (size_t)(e.x & 0xFFFFFu) * HDIM + k8 * 8);
        }
      }
      if (isHandler && myCol < nR) { md = ebuf[nbase + myCol]; mdValid = true; }
    }

    // ---- aggregation GEMM: pacc += P(norm) @ Y ----
    // pmat S2-protected; ys wave-local; stale k-columns have pmat==0.
#pragma unroll
    for (int ks2 = 0; ks2 < 2; ks2++) {
      if (ks2 * 32 < nRows) {  // wave-uniform
        bf16x8 bfv[NT];
#pragma unroll
        for (int nt = 0; nt < NT; nt++)
          bfv[nt] = *(const bf16x8*)&ys[colBase + nt * 16 + l16][ks2 * 32 + quad * 8];
#pragma unroll
        for (int mt = 0; mt < 4; mt++) {
          bf16x8 a = *(const bf16x8*)&pmat[mt * 16 + l16][ks2 * 32 + quad * 8];
#pragma unroll
          for (int nt = 0; nt < NT; nt++)
            pacc[mt][nt] = __builtin_amdgcn_mfma_f32_16x16x32_bf16(a, bfv[nt], pacc[mt][nt], 0, 0, 0);
        }
      }
    }

    bin = nbin; base = nbase; binEnd = nbinEnd; realEnd = nrealEnd;
  }

  // epilogue: each (node, col) owned by exactly one lane -> plain stores
#pragma unroll
  for (int mt = 0; mt < 4; mt++) {
#pragma unroll
    for (int reg = 0; reg < 4; reg++) {
      int node = nodeBase + mt * 16 + quad * 4 + reg;
      if (node < nNodes) {
#pragma unroll
        for (int nt = 0; nt < NT; nt++) {
          int col = colBase + nt * 16 + l16;
          float v = pacc[mt][nt][reg] + bias[col];
          if constexpr (BF16_RELU_OUT)
            ((unsigned short*)Hout)[(size_t)node * OUT + col] = f2bf(fmaxf(v, 0.f));
          else
            ((float*)Hout)[(size_t)node * OUT + col] = v;
        }
      }
    }
  }
}

extern "C" void kernel_launch(void* const* d_in, const int* in_sizes, int n_in,
                              void* d_out, int out_size, void* d_ws, size_t ws_size,
                              hipStream_t stream) {
  const int*   src   = (const int*)d_in[1];
  const int*   dst   = (const int*)d_in[2];
  const int*   etype = (const int*)d_in[3];
  const float* norm  = (const float*)d_in[4];
  const float* emb   = (const float*)d_in[5];
  const float* V1    = (const float*)d_in[6];
  const float* comp1 = (const float*)d_in[7];
  const float* bias1 = (const float*)d_in[8];
  const float* V2    = (const float*)d_in[9];
  const float* comp2 = (const float*)d_in[10];
  const float* bias2 = (const float*)d_in[11];
  float* out = (float*)d_out;

  const int N = in_sizes[0];  // 50000
  const int E = in_sizes[1];  // 1000000
  const int H = 128, O = 64;
  const int NB = (N + DSTBLK - 1) / DSTBLK;  // 782
  const int NBINS = NB * RELS;               // 12512
  const int EPAD_MAX = E + NBINS * 16;

  char* ws = (char*)d_ws;
  size_t off = 0;
  auto alloc = [&](size_t bytes) -> void* {
    void* p = ws + off;
    off += (bytes + 255) & ~(size_t)255;
    return p;
  };
  unsigned short* W1t  = (unsigned short*)alloc(sizeof(short) * RELS * H * H);
  unsigned short* W2t  = (unsigned short*)alloc(sizeof(short) * RELS * O * H);
  unsigned short* embh = (unsigned short*)alloc(sizeof(short) * (size_t)N * H);
  unsigned short* h1b  = (unsigned short*)alloc(sizeof(short) * (size_t)N * H);
  uint2* ebuf = (uint2*)alloc(sizeof(uint2) * EPAD_MAX);
  int* counts  = (int*)alloc(sizeof(int) * NBINS);
  int* cursor  = (int*)alloc(sizeof(int) * NBINS);
  int* offsets = (int*)alloc(sizeof(int) * (NBINS + 1));

  hipMemsetAsync(counts, 0, sizeof(int) * NBINS, stream);
  hipMemsetAsync(cursor, 0, sizeof(int) * NBINS, stream);

  cvt_bf16<<<((size_t)N * H / 8 + 255) / 256, 256, 0, stream>>>(emb, embh, N * H / 8);
  compute_w<<<(RELS * H * H + 255) / 256, 256, 0, stream>>>(comp1, V1, W1t, H);
  compute_w<<<(RELS * O * H + 255) / 256, 256, 0, stream>>>(comp2, V2, W2t, O);
  hist_bins<<<1024, 256, 0, stream>>>(dst, etype, E, NBINS, counts);
  scan_offsets<<<1, 256, 0, stream>>>(counts, offsets, NBINS);
  scatter_bins<<<1024, 256, 0, stream>>>(src, dst, etype, norm, E, offsets, cursor, ebuf);

  rgcn_layer<128, true><<<NB, 256, 0, stream>>>(embh, W1t, ebuf, offsets, counts, bias1, (void*)h1b, N);
  rgcn_layer<64, false><<<NB, 256, 0, stream>>>(h1b, W2t, ebuf, offsets, counts, bias2, (void*)out, N);
}

// Round 7
// 532.439 us; speedup vs baseline: 1.2962x; 1.2962x over previous
//
#include <hip/hip_runtime.h>

// ---------------------------------------------------------------------------
// RGCN (basis decomposition), 2 layers. N=50000, E=1e6, H=128, O=64, R=16.
// Round 7: bisect back to proven mechanisms. Round 6 (global_load_lds with
// scattered per-lane addresses) corrupted results; round 5 (cross-barrier
// VGPR prefetch) spilled. This round = round 4's passing skeleton (in-phase
// register gather, DSTBLK=100 -> 500 blocks ~ the observed ~512 resident
// block slots) + round 5's correctness-proven deltas:
//  - 2 barriers/chunk: pmat maintained by clear-then-set from the owning
//    handler lane (each handler owns a fixed edge column; same-lane program
//    order makes clear->set race-free); norm folded into pmat entries
//    (pmat[dloc][e] = bf16(norm_e)) so the agg GEMM applies it.
//  - ys is wave-local (each wave writes and reads only its own out-column
//    quarter) -> no barrier between GEMM1 and agg.
//  - No per-chunk pmat zeroing (round 4 zeroed 16 KB/chunk).
// No cross-barrier register liveness, no DMA. All MFMA layouts identical to
// rounds 3-5 (passing).
// ---------------------------------------------------------------------------

typedef short bf16x8 __attribute__((ext_vector_type(8)));
typedef float f32x4 __attribute__((ext_vector_type(4)));

#define RELS 16
#define HDIM 128
#define DSTBLK 100
#define MT_P 7  // ceil(DSTBLK/16): pmat has 112 rows

__device__ inline unsigned short f2bf(float f) {
  unsigned int u = __float_as_uint(f);
  unsigned int r = u + 0x7FFFu + ((u >> 16) & 1u);
  return (unsigned short)(r >> 16);
}

__global__ void cvt_bf16(const float* __restrict__ in, unsigned short* __restrict__ out, int n8) {
  int i = blockIdx.x * blockDim.x + threadIdx.x;
  if (i >= n8) return;
  float4 a = ((const float4*)in)[i * 2];
  float4 b = ((const float4*)in)[i * 2 + 1];
  uint4 o;
  o.x = (unsigned)f2bf(a.x) | ((unsigned)f2bf(a.y) << 16);
  o.y = (unsigned)f2bf(a.z) | ((unsigned)f2bf(a.w) << 16);
  o.z = (unsigned)f2bf(b.x) | ((unsigned)f2bf(b.y) << 16);
  o.w = (unsigned)f2bf(b.z) | ((unsigned)f2bf(b.w) << 16);
  ((uint4*)out)[i] = o;
}

// Wt[r][o][k] (bf16, transposed) = sum_b comp[r,b] * V[b,k,o]
__global__ void compute_w(const float* __restrict__ comp, const float* __restrict__ V,
                          unsigned short* __restrict__ Wt, int IO) {
  int idx = blockIdx.x * blockDim.x + threadIdx.x;
  if (idx >= RELS * IO * HDIM) return;
  int k = idx & (HDIM - 1);
  int o = (idx >> 7) % IO;
  int r = idx / (IO * HDIM);
  float s = 0.f;
#pragma unroll
  for (int b = 0; b < RELS; b++)
    s = fmaf(comp[r * RELS + b], V[(size_t)b * HDIM * IO + (size_t)k * IO + o], s);
  Wt[idx] = f2bf(s);
}

__global__ void hist_bins(const int* __restrict__ dst, const int* __restrict__ etype,
                          int n, int nbins, int* __restrict__ counts) {
  __shared__ int lh[8000];
  for (int j = threadIdx.x; j < nbins; j += blockDim.x) lh[j] = 0;
  __syncthreads();
  for (int i = blockIdx.x * blockDim.x + threadIdx.x; i < n; i += gridDim.x * blockDim.x)
    atomicAdd(&lh[(dst[i] / DSTBLK) * RELS + etype[i]], 1);
  __syncthreads();
  for (int j = threadIdx.x; j < nbins; j += blockDim.x) {
    int c = lh[j];
    if (c) atomicAdd(&counts[j], c);
  }
}

// exclusive scan of counts padded to multiples of 16
__global__ void scan_offsets(const int* __restrict__ counts, int* __restrict__ offsets, int nbins) {
  __shared__ int csum[257];
  const int t = threadIdx.x;
  const int CH = (nbins + 255) / 256;
  int lo = t * CH, hi = min(lo + CH, nbins);
  int s = 0;
  for (int i = lo; i < hi; i++) s += (counts[i] + 15) & ~15;
  csum[t + 1] = s;
  if (t == 0) csum[0] = 0;
  __syncthreads();
  if (t == 0)
    for (int i = 1; i <= 256; i++) csum[i] += csum[i - 1];
  __syncthreads();
  int run = csum[t];
  for (int i = lo; i < hi; i++) {
    offsets[i] = run;
    run += (counts[i] + 15) & ~15;
  }
  if (lo < hi && hi == nbins) offsets[nbins] = run;
}

// ebuf[p] = {src | dloc<<20, norm_f32_bits}; dloc = d % DSTBLK (7 bits).
// Pad slots unwritten; all consumers guard by real counts.
__global__ void scatter_bins(const int* __restrict__ src, const int* __restrict__ dst,
                             const int* __restrict__ etype, const float* __restrict__ norm,
                             int n, const int* __restrict__ offsets, int* __restrict__ cursor,
                             uint2* __restrict__ ebuf) {
  for (int i = blockIdx.x * blockDim.x + threadIdx.x; i < n; i += gridDim.x * blockDim.x) {
    int d = dst[i];
    int blk = d / DSTBLK;
    int b = blk * RELS + etype[i];
    int p = offsets[b] + atomicAdd(&cursor[b], 1);
    ebuf[p] = make_uint2((unsigned)src[i] | ((unsigned)(d - blk * DSTBLK) << 20),
                         __float_as_uint(norm[i]));
  }
}

// One block owns DSTBLK nodes; walks its 16 relation bins in 64-edge chunks.
// Per chunk: [S0] in-phase gather of x[src] rows into xs + handler lanes
// clear-then-set pmat[dloc][edge]=bf16(norm); [S2] GEMM1 Y = xs @ W_r staged
// to wave-local ys^T columns; agg GEMM pacc += P(norm) @ Y. Epilogue writes
// each node row once (+bias). Wave w owns out columns [w*OUT/4, +OUT/4).
template <int OUT, bool BF16_RELU_OUT>
__launch_bounds__(256, 2)
__global__ void rgcn_layer(const unsigned short* __restrict__ Xb,  // [N][128] bf16
                           const unsigned short* __restrict__ Wt,  // [R][OUT][128] bf16
                           const uint2* __restrict__ ebuf,
                           const int* __restrict__ offsets, const int* __restrict__ counts,
                           const float* __restrict__ bias, void* __restrict__ Hout,
                           int nNodes) {
  constexpr int NT = OUT / 64;  // 2 (OUT=128) or 1 (OUT=64)
  __shared__ __align__(16) unsigned short xs[64][136];    // gathered src rows
  __shared__ __align__(16) unsigned short ys[OUT][72];    // messages^T, wave-local cols
  __shared__ __align__(16) unsigned short pmat[112][72];  // P[dloc][edge] = bf16(norm)

  const int t = threadIdx.x;
  const int w = t >> 6;
  const int lane = t & 63;
  const int quad = lane >> 4;
  const int l16 = lane & 15;
  const bool isHandler = (t & 3) == 0;
  const int myCol = t >> 2;  // handler-owned edge column (fixed across chunks)
  const int nodeBase = blockIdx.x * DSTBLK;
  const int binBase = blockIdx.x * RELS;
  const int colBase = w * (OUT / 4);

  // one-time zero (stale LDS may hold NaN bit patterns; 0 * NaN = NaN)
  for (int i = t; i < 64 * 136 / 8; i += 256) ((uint4*)xs)[i] = make_uint4(0, 0, 0, 0);
  for (int i = t; i < OUT * 72 / 8; i += 256) ((uint4*)ys)[i] = make_uint4(0, 0, 0, 0);
  for (int i = t; i < 112 * 72 / 8; i += 256) ((uint4*)pmat)[i] = make_uint4(0, 0, 0, 0);

  f32x4 pacc[MT_P][NT] = {};  // persistent dst accumulator
  bool prevValid = false;
  int prevDloc = 0;

  for (int r = 0; r < RELS; r++) {
    const int start = offsets[binBase + r];
    const int end = offsets[binBase + r + 1];
    if (start >= end) continue;
    const int realEnd = start + counts[binBase + r];

    // W fragments for this relation, register-resident for the bin
    const unsigned short* Wr = Wt + (size_t)r * OUT * HDIM;
    bf16x8 wf[4][NT];
#pragma unroll
    for (int ks = 0; ks < 4; ks++)
#pragma unroll
      for (int nt = 0; nt < NT; nt++)
        wf[ks][nt] = *(const bf16x8*)(Wr + (size_t)(colBase + nt * 16 + l16) * HDIM + ks * 32 + quad * 8);

    for (int base = start; base < end; base += 64) {
      const int nRows = min(64, realEnd - base);  // >= 1 always

      __syncthreads();  // S0: previous chunk's xs/pmat readers (GEMM1/agg) done

      // ---- gather phase: x[src] rows -> xs (uint4-vectorized) ----
#pragma unroll
      for (int i = 0; i < 4; i++) {
        int idx = i * 256 + t;
        int row = idx >> 4, k8 = idx & 15;
        if (row < nRows) {
          int s = (int)(ebuf[base + row].x & 0xFFFFFu);
          *(uint4*)&xs[row][k8 * 8] = *(const uint4*)(Xb + (size_t)s * HDIM + k8 * 8);
        }
      }
      // handler lanes: clear-then-set pmat[dloc][myCol] = bf16(norm)
      if (isHandler) {
        if (prevValid) pmat[prevDloc][myCol] = 0;
        if (myCol < nRows) {
          uint2 md = ebuf[base + myCol];
          int dl = (int)(md.x >> 20) & 127;
          pmat[dl][myCol] = f2bf(__uint_as_float(md.y));
          prevDloc = dl;
          prevValid = true;
        } else {
          prevValid = false;
        }
      }

      __syncthreads();  // S2: xs + pmat visible

      // ---- GEMM1: Y = xs @ W_r, staged to wave-local ys^T columns ----
#pragma unroll
      for (int mt = 0; mt < 4; mt++) {
        if (mt * 16 < nRows) {  // wave-uniform
          f32x4 dacc[NT] = {};
#pragma unroll
          for (int ks = 0; ks < 4; ks++) {
            bf16x8 a = *(const bf16x8*)&xs[mt * 16 + l16][ks * 32 + quad * 8];
#pragma unroll
            for (int nt = 0; nt < NT; nt++)
              dacc[nt] = __builtin_amdgcn_mfma_f32_16x16x32_bf16(a, wf[ks][nt], dacc[nt], 0, 0, 0);
          }
#pragma unroll
          for (int nt = 0; nt < NT; nt++) {
            uint2 pk;
            pk.x = (unsigned)f2bf(dacc[nt][0]) | ((unsigned)f2bf(dacc[nt][1]) << 16);
            pk.y = (unsigned)f2bf(dacc[nt][2]) | ((unsigned)f2bf(dacc[nt][3]) << 16);
            *(uint2*)&ys[colBase + nt * 16 + l16][mt * 16 + quad * 4] = pk;
          }
        }
      }

      // ---- aggregation GEMM: pacc += P(norm) @ Y ----
      // pmat S2-protected; ys wave-local (same-wave LDS RAW is in-order);
      // stale ys edge-columns have pmat == 0.
#pragma unroll
      for (int ks2 = 0; ks2 < 2; ks2++) {
        if (ks2 * 32 < nRows) {  // wave-uniform
          bf16x8 bfv[NT];
#pragma unroll
          for (int nt = 0; nt < NT; nt++)
            bfv[nt] = *(const bf16x8*)&ys[colBase + nt * 16 + l16][ks2 * 32 + quad * 8];
#pragma unroll
          for (int mt = 0; mt < MT_P; mt++) {
            bf16x8 a = *(const bf16x8*)&pmat[mt * 16 + l16][ks2 * 32 + quad * 8];
#pragma unroll
            for (int nt = 0; nt < NT; nt++)
              pacc[mt][nt] = __builtin_amdgcn_mfma_f32_16x16x32_bf16(a, bfv[nt], pacc[mt][nt], 0, 0, 0);
          }
        }
      }
    }
  }

  // epilogue: each (node, col) owned by exactly one lane -> plain stores
#pragma unroll
  for (int mt = 0; mt < MT_P; mt++) {
#pragma unroll
    for (int reg = 0; reg < 4; reg++) {
      int ld = mt * 16 + quad * 4 + reg;
      int node = nodeBase + ld;
      if (ld < DSTBLK && node < nNodes) {
#pragma unroll
        for (int nt = 0; nt < NT; nt++) {
          int col = colBase + nt * 16 + l16;
          float v = pacc[mt][nt][reg] + bias[col];
          if constexpr (BF16_RELU_OUT)
            ((unsigned short*)Hout)[(size_t)node * OUT + col] = f2bf(fmaxf(v, 0.f));
          else
            ((float*)Hout)[(size_t)node * OUT + col] = v;
        }
      }
    }
  }
}

extern "C" void kernel_launch(void* const* d_in, const int* in_sizes, int n_in,
                              void* d_out, int out_size, void* d_ws, size_t ws_size,
                              hipStream_t stream) {
  const int*   src   = (const int*)d_in[1];
  const int*   dst   = (const int*)d_in[2];
  const int*   etype = (const int*)d_in[3];
  const float* norm  = (const float*)d_in[4];
  const float* emb   = (const float*)d_in[5];
  const float* V1    = (const float*)d_in[6];
  const float* comp1 = (const float*)d_in[7];
  const float* bias1 = (const float*)d_in[8];
  const float* V2    = (const float*)d_in[9];
  const float* comp2 = (const float*)d_in[10];
  const float* bias2 = (const float*)d_in[11];
  float* out = (float*)d_out;

  const int N = in_sizes[0];  // 50000
  const int E = in_sizes[1];  // 1000000
  const int H = 128, O = 64;
  const int NB = (N + DSTBLK - 1) / DSTBLK;  // 500
  const int NBINS = NB * RELS;               // 8000
  const int EPAD_MAX = E + NBINS * 16;

  char* ws = (char*)d_ws;
  size_t off = 0;
  auto alloc = [&](size_t bytes) -> void* {
    void* p = ws + off;
    off += (bytes + 255) & ~(size_t)255;
    return p;
  };
  unsigned short* W1t  = (unsigned short*)alloc(sizeof(short) * RELS * H * H);
  unsigned short* W2t  = (unsigned short*)alloc(sizeof(short) * RELS * O * H);
  unsigned short* embh = (unsigned short*)alloc(sizeof(short) * (size_t)N * H);
  unsigned short* h1b  = (unsigned short*)alloc(sizeof(short) * (size_t)N * H);
  uint2* ebuf = (uint2*)alloc(sizeof(uint2) * EPAD_MAX);
  int* counts  = (int*)alloc(sizeof(int) * NBINS);
  int* cursor  = (int*)alloc(sizeof(int) * NBINS);
  int* offsets = (int*)alloc(sizeof(int) * (NBINS + 1));

  hipMemsetAsync(counts, 0, sizeof(int) * NBINS, stream);
  hipMemsetAsync(cursor, 0, sizeof(int) * NBINS, stream);

  cvt_bf16<<<((size_t)N * H / 8 + 255) / 256, 256, 0, stream>>>(emb, embh, N * H / 8);
  compute_w<<<(RELS * H * H + 255) / 256, 256, 0, stream>>>(comp1, V1, W1t, H);
  compute_w<<<(RELS * O * H + 255) / 256, 256, 0, stream>>>(comp2, V2, W2t, O);
  hist_bins<<<1024, 256, 0, stream>>>(dst, etype, E, NBINS, counts);
  scan_offsets<<<1, 256, 0, stream>>>(counts, offsets, NBINS);
  scatter_bins<<<1024, 256, 0, stream>>>(src, dst, etype, norm, E, offsets, cursor, ebuf);

  rgcn_layer<128, true><<<NB, 256, 0, stream>>>(embh, W1t, ebuf, offsets, counts, bias1, (void*)h1b, N);
  rgcn_layer<64, false><<<NB, 256, 0, stream>>>(h1b, W2t, ebuf, offsets, counts, bias2, (void*)out, N);
}

// Round 8
// 476.177 us; speedup vs baseline: 1.4494x; 1.1182x over previous
//
#include <hip/hip_runtime.h>

// ---------------------------------------------------------------------------
// RGCN (basis decomposition), 2 layers. N=50000, E=1e6, H=128, O=64, R=16.
// Round 8: round 7 was occupancy-capped at 2 blocks/CU by BOTH the grid
// (500 blocks) and the ~128 KB effective LDS pool (52 KB/block). This round:
// DSTBLK 50 (grid 1000 -> 3.9 blocks/CU) + 32-edge chunks (LDS ~28 KB ->
// 4 blocks fit). pmat shrinks to 64 rows/32 edges -> agg FLOPs/edge -43%.
// All data-flow mechanisms identical to the passing round-7 kernel; only
// tile geometry changes. __launch_bounds__(256,4) to cap VGPR at 128.
// ---------------------------------------------------------------------------

typedef short bf16x8 __attribute__((ext_vector_type(8)));
typedef float f32x4 __attribute__((ext_vector_type(4)));

#define RELS 16
#define HDIM 128
#define DSTBLK 50
#define MT_P 4   // ceil(DSTBLK/16): pmat has 64 rows
#define CHUNK 32

__device__ inline unsigned short f2bf(float f) {
  unsigned int u = __float_as_uint(f);
  unsigned int r = u + 0x7FFFu + ((u >> 16) & 1u);
  return (unsigned short)(r >> 16);
}

__global__ void cvt_bf16(const float* __restrict__ in, unsigned short* __restrict__ out, int n8) {
  int i = blockIdx.x * blockDim.x + threadIdx.x;
  if (i >= n8) return;
  float4 a = ((const float4*)in)[i * 2];
  float4 b = ((const float4*)in)[i * 2 + 1];
  uint4 o;
  o.x = (unsigned)f2bf(a.x) | ((unsigned)f2bf(a.y) << 16);
  o.y = (unsigned)f2bf(a.z) | ((unsigned)f2bf(a.w) << 16);
  o.z = (unsigned)f2bf(b.x) | ((unsigned)f2bf(b.y) << 16);
  o.w = (unsigned)f2bf(b.z) | ((unsigned)f2bf(b.w) << 16);
  ((uint4*)out)[i] = o;
}

// Wt[r][o][k] (bf16, transposed) = sum_b comp[r,b] * V[b,k,o]
__global__ void compute_w(const float* __restrict__ comp, const float* __restrict__ V,
                          unsigned short* __restrict__ Wt, int IO) {
  int idx = blockIdx.x * blockDim.x + threadIdx.x;
  if (idx >= RELS * IO * HDIM) return;
  int k = idx & (HDIM - 1);
  int o = (idx >> 7) % IO;
  int r = idx / (IO * HDIM);
  float s = 0.f;
#pragma unroll
  for (int b = 0; b < RELS; b++)
    s = fmaf(comp[r * RELS + b], V[(size_t)b * HDIM * IO + (size_t)k * IO + o], s);
  Wt[idx] = f2bf(s);
}

__global__ void hist_bins(const int* __restrict__ dst, const int* __restrict__ etype,
                          int n, int nbins, int* __restrict__ counts) {
  __shared__ int lh[16000];
  for (int j = threadIdx.x; j < nbins; j += blockDim.x) lh[j] = 0;
  __syncthreads();
  for (int i = blockIdx.x * blockDim.x + threadIdx.x; i < n; i += gridDim.x * blockDim.x)
    atomicAdd(&lh[(dst[i] / DSTBLK) * RELS + etype[i]], 1);
  __syncthreads();
  for (int j = threadIdx.x; j < nbins; j += blockDim.x) {
    int c = lh[j];
    if (c) atomicAdd(&counts[j], c);
  }
}

// exclusive scan of counts padded to multiples of 16
__global__ void scan_offsets(const int* __restrict__ counts, int* __restrict__ offsets, int nbins) {
  __shared__ int csum[257];
  const int t = threadIdx.x;
  const int CH = (nbins + 255) / 256;
  int lo = t * CH, hi = min(lo + CH, nbins);
  int s = 0;
  for (int i = lo; i < hi; i++) s += (counts[i] + 15) & ~15;
  csum[t + 1] = s;
  if (t == 0) csum[0] = 0;
  __syncthreads();
  if (t == 0)
    for (int i = 1; i <= 256; i++) csum[i] += csum[i - 1];
  __syncthreads();
  int run = csum[t];
  for (int i = lo; i < hi; i++) {
    offsets[i] = run;
    run += (counts[i] + 15) & ~15;
  }
  if (lo < hi && hi == nbins) offsets[nbins] = run;
}

// ebuf[p] = {src | dloc<<20, norm_f32_bits}; dloc = d % DSTBLK (6 bits).
// Pad slots unwritten; all consumers guard by real counts.
__global__ void scatter_bins(const int* __restrict__ src, const int* __restrict__ dst,
                             const int* __restrict__ etype, const float* __restrict__ norm,
                             int n, const int* __restrict__ offsets, int* __restrict__ cursor,
                             uint2* __restrict__ ebuf) {
  for (int i = blockIdx.x * blockDim.x + threadIdx.x; i < n; i += gridDim.x * blockDim.x) {
    int d = dst[i];
    int blk = d / DSTBLK;
    int b = blk * RELS + etype[i];
    int p = offsets[b] + atomicAdd(&cursor[b], 1);
    ebuf[p] = make_uint2((unsigned)src[i] | ((unsigned)(d - blk * DSTBLK) << 20),
                         __float_as_uint(norm[i]));
  }
}

// One block owns DSTBLK nodes; walks its 16 relation bins in 32-edge chunks.
// Per chunk: [S0] gather x[src] rows into xs + handler lanes clear-then-set
// pmat[dloc][edge]=bf16(norm); [S2] GEMM1 Y = xs @ W_r staged to wave-local
// ys^T columns; agg GEMM pacc += P(norm) @ Y (single k=32 pass). Epilogue
// writes each node row once (+bias). Wave w owns out cols [w*OUT/4, +OUT/4).
template <int OUT, bool BF16_RELU_OUT>
__launch_bounds__(256, 4)
__global__ void rgcn_layer(const unsigned short* __restrict__ Xb,  // [N][128] bf16
                           const unsigned short* __restrict__ Wt,  // [R][OUT][128] bf16
                           const uint2* __restrict__ ebuf,
                           const int* __restrict__ offsets, const int* __restrict__ counts,
                           const float* __restrict__ bias, void* __restrict__ Hout,
                           int nNodes) {
  constexpr int NT = OUT / 64;  // 2 (OUT=128) or 1 (OUT=64)
  __shared__ __align__(16) unsigned short xs[CHUNK][136];  // gathered src rows
  __shared__ __align__(16) unsigned short ys[OUT][40];     // messages^T, wave-local cols
  __shared__ __align__(16) unsigned short pmat[64][40];    // P[dloc][edge] = bf16(norm)

  const int t = threadIdx.x;
  const int w = t >> 6;
  const int lane = t & 63;
  const int quad = lane >> 4;
  const int l16 = lane & 15;
  const bool isHandler = (t & 7) == 0;
  const int myCol = t >> 3;  // handler-owned edge column (0..31, fixed)
  const int nodeBase = blockIdx.x * DSTBLK;
  const int binBase = blockIdx.x * RELS;
  const int colBase = w * (OUT / 4);

  // one-time zero (stale LDS may hold NaN bit patterns; 0 * NaN = NaN)
  for (int i = t; i < CHUNK * 136 / 8; i += 256) ((uint4*)xs)[i] = make_uint4(0, 0, 0, 0);
  for (int i = t; i < OUT * 40 / 8; i += 256) ((uint4*)ys)[i] = make_uint4(0, 0, 0, 0);
  for (int i = t; i < 64 * 40 / 8; i += 256) ((uint4*)pmat)[i] = make_uint4(0, 0, 0, 0);

  f32x4 pacc[MT_P][NT] = {};  // persistent dst accumulator
  bool prevValid = false;
  int prevDloc = 0;

  for (int r = 0; r < RELS; r++) {
    const int start = offsets[binBase + r];
    const int end = offsets[binBase + r + 1];
    if (start >= end) continue;
    const int realEnd = start + counts[binBase + r];

    // W fragments for this relation, register-resident for the bin
    const unsigned short* Wr = Wt + (size_t)r * OUT * HDIM;
    bf16x8 wf[4][NT];
#pragma unroll
    for (int ks = 0; ks < 4; ks++)
#pragma unroll
      for (int nt = 0; nt < NT; nt++)
        wf[ks][nt] = *(const bf16x8*)(Wr + (size_t)(colBase + nt * 16 + l16) * HDIM + ks * 32 + quad * 8);

    for (int base = start; base < end; base += CHUNK) {
      const int nRows = min(CHUNK, realEnd - base);  // 16 or 32

      __syncthreads();  // S0: previous chunk's xs/pmat readers done

      // ---- gather phase: x[src] rows -> xs (uint4-vectorized) ----
#pragma unroll
      for (int i = 0; i < 2; i++) {
        int idx = i * 256 + t;
        int row = idx >> 4, k8 = idx & 15;
        if (row < nRows) {
          int s = (int)(ebuf[base + row].x & 0xFFFFFu);
          *(uint4*)&xs[row][k8 * 8] = *(const uint4*)(Xb + (size_t)s * HDIM + k8 * 8);
        }
      }
      // handler lanes: clear-then-set pmat[dloc][myCol] = bf16(norm)
      if (isHandler) {
        if (prevValid) pmat[prevDloc][myCol] = 0;
        if (myCol < nRows) {
          uint2 md = ebuf[base + myCol];
          int dl = (int)(md.x >> 20) & 63;
          pmat[dl][myCol] = f2bf(__uint_as_float(md.y));
          prevDloc = dl;
          prevValid = true;
        } else {
          prevValid = false;
        }
      }

      __syncthreads();  // S2: xs + pmat visible

      // ---- GEMM1: Y = xs @ W_r, staged to wave-local ys^T columns ----
#pragma unroll
      for (int mt = 0; mt < 2; mt++) {
        if (mt * 16 < nRows) {  // wave-uniform
          f32x4 dacc[NT] = {};
#pragma unroll
          for (int ks = 0; ks < 4; ks++) {
            bf16x8 a = *(const bf16x8*)&xs[mt * 16 + l16][ks * 32 + quad * 8];
#pragma unroll
            for (int nt = 0; nt < NT; nt++)
              dacc[nt] = __builtin_amdgcn_mfma_f32_16x16x32_bf16(a, wf[ks][nt], dacc[nt], 0, 0, 0);
          }
#pragma unroll
          for (int nt = 0; nt < NT; nt++) {
            uint2 pk;
            pk.x = (unsigned)f2bf(dacc[nt][0]) | ((unsigned)f2bf(dacc[nt][1]) << 16);
            pk.y = (unsigned)f2bf(dacc[nt][2]) | ((unsigned)f2bf(dacc[nt][3]) << 16);
            *(uint2*)&ys[colBase + nt * 16 + l16][mt * 16 + quad * 4] = pk;
          }
        }
      }

      // ---- aggregation GEMM: pacc += P(norm) @ Y (single k=32 pass) ----
      // pmat S2-protected; ys wave-local (same-wave LDS RAW is in-order);
      // stale ys edge-columns have pmat == 0.
      {
        bf16x8 bfv[NT];
#pragma unroll
        for (int nt = 0; nt < NT; nt++)
          bfv[nt] = *(const bf16x8*)&ys[colBase + nt * 16 + l16][quad * 8];
#pragma unroll
        for (int mt = 0; mt < MT_P; mt++) {
          bf16x8 a = *(const bf16x8*)&pmat[mt * 16 + l16][quad * 8];
#pragma unroll
          for (int nt = 0; nt < NT; nt++)
            pacc[mt][nt] = __builtin_amdgcn_mfma_f32_16x16x32_bf16(a, bfv[nt], pacc[mt][nt], 0, 0, 0);
        }
      }
    }
  }

  // epilogue: each (node, col) owned by exactly one lane -> plain stores
#pragma unroll
  for (int mt = 0; mt < MT_P; mt++) {
#pragma unroll
    for (int reg = 0; reg < 4; reg++) {
      int ld = mt * 16 + quad * 4 + reg;
      int node = nodeBase + ld;
      if (ld < DSTBLK && node < nNodes) {
#pragma unroll
        for (int nt = 0; nt < NT; nt++) {
          int col = colBase + nt * 16 + l16;
          float v = pacc[mt][nt][reg] + bias[col];
          if constexpr (BF16_RELU_OUT)
            ((unsigned short*)Hout)[(size_t)node * OUT + col] = f2bf(fmaxf(v, 0.f));
          else
            ((float*)Hout)[(size_t)node * OUT + col] = v;
        }
      }
    }
  }
}

extern "C" void kernel_launch(void* const* d_in, const int* in_sizes, int n_in,
                              void* d_out, int out_size, void* d_ws, size_t ws_size,
                              hipStream_t stream) {
  const int*   src   = (const int*)d_in[1];
  const int*   dst   = (const int*)d_in[2];
  const int*   etype = (const int*)d_in[3];
  const float* norm  = (const float*)d_in[4];
  const float* emb   = (const float*)d_in[5];
  const float* V1    = (const float*)d_in[6];
  const float* comp1 = (const float*)d_in[7];
  const float* bias1 = (const float*)d_in[8];
  const float* V2    = (const float*)d_in[9];
  const float* comp2 = (const float*)d_in[10];
  const float* bias2 = (const float*)d_in[11];
  float* out = (float*)d_out;

  const int N = in_sizes[0];  // 50000
  const int E = in_sizes[1];  // 1000000
  const int H = 128, O = 64;
  const int NB = (N + DSTBLK - 1) / DSTBLK;  // 1000
  const int NBINS = NB * RELS;               // 16000
  const int EPAD_MAX = E + NBINS * 16;

  char* ws = (char*)d_ws;
  size_t off = 0;
  auto alloc = [&](size_t bytes) -> void* {
    void* p = ws + off;
    off += (bytes + 255) & ~(size_t)255;
    return p;
  };
  unsigned short* W1t  = (unsigned short*)alloc(sizeof(short) * RELS * H * H);
  unsigned short* W2t  = (unsigned short*)alloc(sizeof(short) * RELS * O * H);
  unsigned short* embh = (unsigned short*)alloc(sizeof(short) * (size_t)N * H);
  unsigned short* h1b  = (unsigned short*)alloc(sizeof(short) * (size_t)N * H);
  uint2* ebuf = (uint2*)alloc(sizeof(uint2) * EPAD_MAX);
  int* counts  = (int*)alloc(sizeof(int) * NBINS);
  int* cursor  = (int*)alloc(sizeof(int) * NBINS);
  int* offsets = (int*)alloc(sizeof(int) * (NBINS + 1));

  hipMemsetAsync(counts, 0, sizeof(int) * NBINS, stream);
  hipMemsetAsync(cursor, 0, sizeof(int) * NBINS, stream);

  cvt_bf16<<<((size_t)N * H / 8 + 255) / 256, 256, 0, stream>>>(emb, embh, N * H / 8);
  compute_w<<<(RELS * H * H + 255) / 256, 256, 0, stream>>>(comp1, V1, W1t, H);
  compute_w<<<(RELS * O * H + 255) / 256, 256, 0, stream>>>(comp2, V2, W2t, O);
  hist_bins<<<1024, 256, 0, stream>>>(dst, etype, E, NBINS, counts);
  scan_offsets<<<1, 256, 0, stream>>>(counts, offsets, NBINS);
  scatter_bins<<<1024, 256, 0, stream>>>(src, dst, etype, norm, E, offsets, cursor, ebuf);

  rgcn_layer<128, true><<<NB, 256, 0, stream>>>(embh, W1t, ebuf, offsets, counts, bias1, (void*)h1b, N);
  rgcn_layer<64, false><<<NB, 256, 0, stream>>>(h1b, W2t, ebuf, offsets, counts, bias2, (void*)out, N);
}

// Round 9
// 460.787 us; speedup vs baseline: 1.4978x; 1.0334x over previous
//
#include <hip/hip_runtime.h>

// ---------------------------------------------------------------------------
// RGCN (basis decomposition), 2 layers. N=50000, E=1e6, H=128, O=64, R=16.
// Round 9: round 8 was exposed-latency-bound per chunk (S0 -> ebuf ~250cyc ->
// dependent gather ~300-900cyc -> S2 -> ~400cyc compute; MfmaUtil 15.6%).
// Changes:
//  - Single barrier per chunk with double-buffered xs/pmat. Phase k: issue
//    ebuf(k+1) loads; GEMM1 (covers ebuf); issue gathers(k+1); agg (covers
//    gather); write regs -> xs[cb^1]/pmat[cb^1]; barrier. All register
//    liveness stays WITHIN one phase (round 5's failure was liveness across
//    barriers).
//  - DSTBLK 66 -> grid 758 <= 768 residency slots (3 blocks/CU @ 40.4 KB
//    LDS): one residency round, no grid quantization tail.
//  - Preprocessing: hist grid 256 (4x fewer 12k-entry LDS scans);
//    scan_offsets serial 256-loop -> Hillis-Steele; bins 16000 -> 12128.
// MFMA layouts identical to rounds 3-8 (passing).
// ---------------------------------------------------------------------------

typedef short bf16x8 __attribute__((ext_vector_type(8)));
typedef float f32x4 __attribute__((ext_vector_type(4)));

#define RELS 16
#define HDIM 128
#define DSTBLK 66
#define MT_P 5    // ceil(66/16): pmat has 80 rows
#define CHUNK 32
#define MAXBINS 12288

__device__ inline unsigned short f2bf(float f) {
  unsigned int u = __float_as_uint(f);
  unsigned int r = u + 0x7FFFu + ((u >> 16) & 1u);
  return (unsigned short)(r >> 16);
}

__global__ void cvt_bf16(const float* __restrict__ in, unsigned short* __restrict__ out, int n8) {
  int i = blockIdx.x * blockDim.x + threadIdx.x;
  if (i >= n8) return;
  float4 a = ((const float4*)in)[i * 2];
  float4 b = ((const float4*)in)[i * 2 + 1];
  uint4 o;
  o.x = (unsigned)f2bf(a.x) | ((unsigned)f2bf(a.y) << 16);
  o.y = (unsigned)f2bf(a.z) | ((unsigned)f2bf(a.w) << 16);
  o.z = (unsigned)f2bf(b.x) | ((unsigned)f2bf(b.y) << 16);
  o.w = (unsigned)f2bf(b.z) | ((unsigned)f2bf(b.w) << 16);
  ((uint4*)out)[i] = o;
}

// Wt[r][o][k] (bf16, transposed) = sum_b comp[r,b] * V[b,k,o]
__global__ void compute_w(const float* __restrict__ comp, const float* __restrict__ V,
                          unsigned short* __restrict__ Wt, int IO) {
  int idx = blockIdx.x * blockDim.x + threadIdx.x;
  if (idx >= RELS * IO * HDIM) return;
  int k = idx & (HDIM - 1);
  int o = (idx >> 7) % IO;
  int r = idx / (IO * HDIM);
  float s = 0.f;
#pragma unroll
  for (int b = 0; b < RELS; b++)
    s = fmaf(comp[r * RELS + b], V[(size_t)b * HDIM * IO + (size_t)k * IO + o], s);
  Wt[idx] = f2bf(s);
}

__global__ void hist_bins(const int* __restrict__ dst, const int* __restrict__ etype,
                          int n, int nbins, int* __restrict__ counts) {
  __shared__ int lh[MAXBINS];
  for (int j = threadIdx.x; j < nbins; j += blockDim.x) lh[j] = 0;
  __syncthreads();
  for (int i = blockIdx.x * blockDim.x + threadIdx.x; i < n; i += gridDim.x * blockDim.x)
    atomicAdd(&lh[(dst[i] / DSTBLK) * RELS + etype[i]], 1);
  __syncthreads();
  for (int j = threadIdx.x; j < nbins; j += blockDim.x) {
    int c = lh[j];
    if (c) atomicAdd(&counts[j], c);
  }
}

// exclusive scan of counts padded to multiples of 16 (parallel prefix)
__global__ void scan_offsets(const int* __restrict__ counts, int* __restrict__ offsets, int nbins) {
  __shared__ int csum[256];
  const int t = threadIdx.x;
  const int CH = (nbins + 255) / 256;
  int lo = t * CH, hi = min(lo + CH, nbins);
  int s = 0;
  for (int i = lo; i < hi; i++) s += (counts[i] + 15) & ~15;
  csum[t] = s;
  __syncthreads();
#pragma unroll
  for (int d = 1; d < 256; d <<= 1) {  // Hillis-Steele inclusive scan
    int v = (t >= d) ? csum[t - d] : 0;
    __syncthreads();
    csum[t] += v;
    __syncthreads();
  }
  int run = (t == 0) ? 0 : csum[t - 1];
  for (int i = lo; i < hi; i++) {
    offsets[i] = run;
    run += (counts[i] + 15) & ~15;
  }
  if (lo < nbins && hi == nbins) offsets[nbins] = run;
}

// ebuf[p] = {src | dloc<<20, norm_f32_bits}; dloc = d % DSTBLK (7 bits).
// Pad slots unwritten; all consumers guard by real counts.
__global__ void scatter_bins(const int* __restrict__ src, const int* __restrict__ dst,
                             const int* __restrict__ etype, const float* __restrict__ norm,
                             int n, const int* __restrict__ offsets, int* __restrict__ cursor,
                             uint2* __restrict__ ebuf) {
  for (int i = blockIdx.x * blockDim.x + threadIdx.x; i < n; i += gridDim.x * blockDim.x) {
    int d = dst[i];
    int blk = d / DSTBLK;
    int b = blk * RELS + etype[i];
    int p = offsets[b] + atomicAdd(&cursor[b], 1);
    ebuf[p] = make_uint2((unsigned)src[i] | ((unsigned)(d - blk * DSTBLK) << 20),
                         __float_as_uint(norm[i]));
  }
}

// One block owns DSTBLK nodes; walks its 16 relation bins in 32-edge chunks.
// Single barrier per chunk; xs/pmat double-buffered; chunk k+1's ebuf loads
// issue before GEMM1(k), its gathers before agg(k), writes before the
// barrier. Wave w owns out columns [w*OUT/4, +OUT/4).
template <int OUT, bool BF16_RELU_OUT>
__launch_bounds__(256, 3)
__global__ void rgcn_layer(const unsigned short* __restrict__ Xb,  // [N][128] bf16
                           const unsigned short* __restrict__ Wt,  // [R][OUT][128] bf16
                           const uint2* __restrict__ ebuf,
                           const int* __restrict__ offsets, const int* __restrict__ counts,
                           const float* __restrict__ bias, void* __restrict__ Hout,
                           int nNodes) {
  constexpr int NT = OUT / 64;  // 2 (OUT=128) or 1 (OUT=64)
  __shared__ __align__(16) unsigned short xs[2][CHUNK][136];  // gathered src rows
  __shared__ __align__(16) unsigned short ys[OUT][40];        // messages^T, wave-local cols
  __shared__ __align__(16) unsigned short pmat[2][80][40];    // P[dloc][edge] = bf16(norm)

  const int t = threadIdx.x;
  const int w = t >> 6;
  const int lane = t & 63;
  const int quad = lane >> 4;
  const int l16 = lane & 15;
  const int r0 = t >> 4;     // gather row (this thread covers rows r0, r0+16)
  const int k8 = t & 15;     // gather 8-elem column piece
  const bool isHandler = (t & 7) == 0;
  const int myCol = t >> 3;  // handler-owned edge column (0..31, fixed)
  const int nodeBase = blockIdx.x * DSTBLK;
  const int binBase = blockIdx.x * RELS;
  const int colBase = w * (OUT / 4);

  // one-time zero (stale LDS may hold NaN bit patterns; 0 * NaN = NaN)
  for (int i = t; i < 2 * CHUNK * 136 / 8; i += 256) ((uint4*)xs)[i] = make_uint4(0, 0, 0, 0);
  for (int i = t; i < OUT * 40 / 8; i += 256) ((uint4*)ys)[i] = make_uint4(0, 0, 0, 0);
  for (int i = t; i < 2 * 80 * 40 / 8; i += 256) ((uint4*)pmat)[i] = make_uint4(0, 0, 0, 0);

  f32x4 pacc[MT_P][NT] = {};  // persistent dst accumulator

  // first nonempty bin
  int bin = 0, base = 0, binEnd = 0, realEnd = 0;
  for (; bin < RELS; bin++) {
    base = offsets[binBase + bin];
    binEnd = offsets[binBase + bin + 1];
    if (base < binEnd) { realEnd = base + counts[binBase + bin]; break; }
  }

  __syncthreads();  // zero-init visible before prologue LDS writes

  // prologue: load chunk 0 into xs[0]/pmat[0] (full latency exposed once)
  int pdA = -1, pdB = -1;  // handler prev-entry trackers (pdA = buffer written next)
  if (bin < RELS) {
    int nR = min(CHUNK, realEnd - base);
    if (r0 < nR) {
      uint2 e = ebuf[base + r0];
      *(uint4*)&xs[0][r0][k8 * 8] = *(const uint4*)(Xb + (size_t)(e.x & 0xFFFFFu) * HDIM + k8 * 8);
    }
    if (16 + r0 < nR) {
      uint2 e = ebuf[base + 16 + r0];
      *(uint4*)&xs[0][16 + r0][k8 * 8] = *(const uint4*)(Xb + (size_t)(e.x & 0xFFFFFu) * HDIM + k8 * 8);
    }
    if (isHandler && myCol < nR) {
      uint2 m = ebuf[base + myCol];
      int dl = (int)(m.x >> 20) & 127;
      pmat[0][dl][myCol] = f2bf(__uint_as_float(m.y));
      pdB = dl;  // next write to buffer 0 happens two phases from now (tracker pdB)
    }
  }
  __syncthreads();

  int cb = 0;
  int curRel = -1;
  bf16x8 wf[4][NT];

  while (bin < RELS) {
    const int nRows = min(CHUNK, realEnd - base);

    if (bin != curRel) {  // W fragments for this relation (register-resident)
      curRel = bin;
      const unsigned short* Wr = Wt + (size_t)bin * OUT * HDIM;
#pragma unroll
      for (int ks = 0; ks < 4; ks++)
#pragma unroll
        for (int nt = 0; nt < NT; nt++)
          wf[ks][nt] = *(const bf16x8*)(Wr + (size_t)(colBase + nt * 16 + l16) * HDIM + ks * 32 + quad * 8);
    }

    // next chunk coords (scalar)
    int nbin = bin, nbase = base + CHUNK, nbinEnd = binEnd, nrealEnd = realEnd;
    if (nbase >= binEnd) {
      for (nbin = bin + 1; nbin < RELS; nbin++) {
        nbase = offsets[binBase + nbin];
        nbinEnd = offsets[binBase + nbin + 1];
        if (nbase < nbinEnd) { nrealEnd = nbase + counts[binBase + nbin]; break; }
      }
    }
    const bool hasNext = nbin < RELS;
    const int nR = hasNext ? min(CHUNK, nrealEnd - nbase) : 0;

    // ---- issue next chunk's ebuf loads (latency covered by GEMM1) ----
    uint2 e0, e1, em;
    if (hasNext) {
      if (r0 < nR) e0 = ebuf[nbase + r0];
      if (16 + r0 < nR) e1 = ebuf[nbase + 16 + r0];
      if (isHandler && myCol < nR) em = ebuf[nbase + myCol];
    }

    // ---- GEMM1: Y = xs[cb] @ W_r, staged to wave-local ys^T columns ----
#pragma unroll
    for (int mt = 0; mt < 2; mt++) {
      if (mt * 16 < nRows) {  // wave-uniform
        f32x4 dacc[NT] = {};
#pragma unroll
        for (int ks = 0; ks < 4; ks++) {
          bf16x8 a = *(const bf16x8*)&xs[cb][mt * 16 + l16][ks * 32 + quad * 8];
#pragma unroll
          for (int nt = 0; nt < NT; nt++)
            dacc[nt] = __builtin_amdgcn_mfma_f32_16x16x32_bf16(a, wf[ks][nt], dacc[nt], 0, 0, 0);
        }
#pragma unroll
        for (int nt = 0; nt < NT; nt++) {
          uint2 pk;
          pk.x = (unsigned)f2bf(dacc[nt][0]) | ((unsigned)f2bf(dacc[nt][1]) << 16);
          pk.y = (unsigned)f2bf(dacc[nt][2]) | ((unsigned)f2bf(dacc[nt][3]) << 16);
          *(uint2*)&ys[colBase + nt * 16 + l16][mt * 16 + quad * 4] = pk;
        }
      }
    }

    // ---- issue next chunk's gathers (latency covered by agg) ----
    uint4 g0, g1;
    if (hasNext) {
      if (r0 < nR) g0 = *(const uint4*)(Xb + (size_t)(e0.x & 0xFFFFFu) * HDIM + k8 * 8);
      if (16 + r0 < nR) g1 = *(const uint4*)(Xb + (size_t)(e1.x & 0xFFFFFu) * HDIM + k8 * 8);
    }

    // ---- aggregation GEMM: pacc += P(norm) @ Y (single k=32 pass) ----
    // pmat[cb] barrier-protected; ys wave-local (same-wave LDS RAW in-order);
    // stale ys edge-columns have pmat == 0.
    {
      bf16x8 bfv[NT];
#pragma unroll
      for (int nt = 0; nt < NT; nt++)
        bfv[nt] = *(const bf16x8*)&ys[colBase + nt * 16 + l16][quad * 8];
#pragma unroll
      for (int mt = 0; mt < MT_P; mt++) {
        bf16x8 a = *(const bf16x8*)&pmat[cb][mt * 16 + l16][quad * 8];
#pragma unroll
        for (int nt = 0; nt < NT; nt++)
          pacc[mt][nt] = __builtin_amdgcn_mfma_f32_16x16x32_bf16(a, bfv[nt], pacc[mt][nt], 0, 0, 0);
      }
    }

    // ---- write next chunk into the other buffers (before the barrier) ----
    if (hasNext) {
      if (r0 < nR) *(uint4*)&xs[cb ^ 1][r0][k8 * 8] = g0;
      if (16 + r0 < nR) *(uint4*)&xs[cb ^ 1][16 + r0][k8 * 8] = g1;
      if (isHandler) {
        if (pdA >= 0) pmat[cb ^ 1][pdA][myCol] = 0;  // clear own old entry
        if (myCol < nR) {
          int dl = (int)(em.x >> 20) & 127;
          pmat[cb ^ 1][dl][myCol] = f2bf(__uint_as_float(em.y));
          pdA = dl;
        } else {
          pdA = -1;
        }
      }
    }
    { int tmp = pdA; pdA = pdB; pdB = tmp; }  // tracker follows buffer parity

    if (hasNext) __syncthreads();  // block-uniform condition

    bin = nbin; base = nbase; binEnd = nbinEnd; realEnd = nrealEnd;
    cb ^= 1;
  }

  // epilogue: each (node, col) owned by exactly one lane -> plain stores
#pragma unroll
  for (int mt = 0; mt < MT_P; mt++) {
#pragma unroll
    for (int reg = 0; reg < 4; reg++) {
      int ld = mt * 16 + quad * 4 + reg;
      int node = nodeBase + ld;
      if (ld < DSTBLK && node < nNodes) {
#pragma unroll
        for (int nt = 0; nt < NT; nt++) {
          int col = colBase + nt * 16 + l16;
          float v = pacc[mt][nt][reg] + bias[col];
          if constexpr (BF16_RELU_OUT)
            ((unsigned short*)Hout)[(size_t)node * OUT + col] = f2bf(fmaxf(v, 0.f));
          else
            ((float*)Hout)[(size_t)node * OUT + col] = v;
        }
      }
    }
  }
}

extern "C" void kernel_launch(void* const* d_in, const int* in_sizes, int n_in,
                              void* d_out, int out_size, void* d_ws, size_t ws_size,
                              hipStream_t stream) {
  const int*   src   = (const int*)d_in[1];
  const int*   dst   = (const int*)d_in[2];
  const int*   etype = (const int*)d_in[3];
  const float* norm  = (const float*)d_in[4];
  const float* emb   = (const float*)d_in[5];
  const float* V1    = (const float*)d_in[6];
  const float* comp1 = (const float*)d_in[7];
  const float* bias1 = (const float*)d_in[8];
  const float* V2    = (const float*)d_in[9];
  const float* comp2 = (const float*)d_in[10];
  const float* bias2 = (const float*)d_in[11];
  float* out = (float*)d_out;

  const int N = in_sizes[0];  // 50000
  const int E = in_sizes[1];  // 1000000
  const int H = 128, O = 64;
  const int NB = (N + DSTBLK - 1) / DSTBLK;  // 758
  const int NBINS = NB * RELS;               // 12128
  const int EPAD_MAX = E + NBINS * 16;

  char* ws = (char*)d_ws;
  size_t off = 0;
  auto alloc = [&](size_t bytes) -> void* {
    void* p = ws + off;
    off += (bytes + 255) & ~(size_t)255;
    return p;
  };
  unsigned short* W1t  = (unsigned short*)alloc(sizeof(short) * RELS * H * H);
  unsigned short* W2t  = (unsigned short*)alloc(sizeof(short) * RELS * O * H);
  unsigned short* embh = (unsigned short*)alloc(sizeof(short) * (size_t)N * H);
  unsigned short* h1b  = (unsigned short*)alloc(sizeof(short) * (size_t)N * H);
  uint2* ebuf = (uint2*)alloc(sizeof(uint2) * EPAD_MAX);
  int* counts  = (int*)alloc(sizeof(int) * NBINS);
  int* cursor  = (int*)alloc(sizeof(int) * NBINS);
  int* offsets = (int*)alloc(sizeof(int) * (NBINS + 1));

  hipMemsetAsync(counts, 0, sizeof(int) * NBINS, stream);
  hipMemsetAsync(cursor, 0, sizeof(int) * NBINS, stream);

  cvt_bf16<<<((size_t)N * H / 8 + 255) / 256, 256, 0, stream>>>(emb, embh, N * H / 8);
  compute_w<<<(RELS * H * H + 255) / 256, 256, 0, stream>>>(comp1, V1, W1t, H);
  compute_w<<<(RELS * O * H + 255) / 256, 256, 0, stream>>>(comp2, V2, W2t, O);
  hist_bins<<<256, 256, 0, stream>>>(dst, etype, E, NBINS, counts);
  scan_offsets<<<1, 256, 0, stream>>>(counts, offsets, NBINS);
  scatter_bins<<<1024, 256, 0, stream>>>(src, dst, etype, norm, E, offsets, cursor, ebuf);

  rgcn_layer<128, true><<<NB, 256, 0, stream>>>(embh, W1t, ebuf, offsets, counts, bias1, (void*)h1b, N);
  rgcn_layer<64, false><<<NB, 256, 0, stream>>>(h1b, W2t, ebuf, offsets, counts, bias2, (void*)out, N);
}